// Round 1
// 799.241 us; speedup vs baseline: 1.0572x; 1.0572x over previous
//
#include <hip/hip_runtime.h>

// Problem constants
#define Bv    32
#define Lv    512
#define Hv    512
#define Fv    512
#define Tv    4096
#define Mv    (Bv*Lv)          // 16384 rows
#define NBINSv 256

// d_out layout (floats): out(B,T,H) | pit(B,L) | eng(B,L) | log_dur(B,L) | mel_len(B)
#define OUT_OFF 0
#define PIT_OFF (Bv*(size_t)Tv*Hv)              // 67108864
#define ENG_OFF (PIT_OFF + Mv)
#define DUR_OFF (ENG_OFF + Mv)
#define MEL_OFF (DUR_OFF + Mv)

typedef unsigned short ushort;
typedef __attribute__((ext_vector_type(8))) short   bf16x8;   // 8 bf16 in 4 VGPRs
typedef __attribute__((ext_vector_type(4))) float   f32x4;
typedef __attribute__((ext_vector_type(8))) unsigned short u16x8;

__device__ __forceinline__ float b2f(ushort u) {
    union { float f; unsigned u; } x; x.u = ((unsigned)u) << 16; return x.f;
}
__device__ __forceinline__ ushort f2b(float f) {
    union { float f; unsigned u; } x; x.f = f;
    unsigned r = x.u + 0x7fffu + ((x.u >> 16) & 1u);   // RNE
    return (ushort)(r >> 16);
}

#define GLL16(g, l) __builtin_amdgcn_global_load_lds( \
    (const __attribute__((address_space(1))) void*)(g), \
    (__attribute__((address_space(3))) void*)(l), 16, 0, 0)

#define FENCE() asm volatile("" ::: "memory")
#define BAR() do { FENCE(); __builtin_amdgcn_s_barrier(); FENCE(); } while (0)
#define VMCNT(N) asm volatile("s_waitcnt vmcnt(" #N ")" ::: "memory")

// Struct-of-pointers kernel args for z-batched launches
template<int NZ> struct GArgs {
    const ushort* A[NZ];
    const ushort* W[NZ];
    const float*  bias[NZ];
    ushort*       C[NZ];
};
struct RmsArgs   { const ushort* h[3]; const float* g[3]; ushort* o[3]; };
struct RlArgs    { const ushort* h[3]; const float* g[3]; const float* wl[3]; const float* bl[3]; };
struct TransArgs { const float* src[6]; ushort* dst[6]; };
struct ConvArgs  { const float* src[2]; ushort* dst[2]; };

// 16 MFMA cluster under setprio: i-quadrant IOFF (a_f holds that half), j-quadrant JOFF
#define MFMA_Q(IOFF, JOFF)                                               \
    do {                                                                 \
        __builtin_amdgcn_s_setprio(1);                                   \
        _Pragma("unroll")                                                \
        for (int s_ = 0; s_ < 2; ++s_)                                   \
            _Pragma("unroll")                                            \
            for (int i_ = 0; i_ < 4; ++i_)                               \
                _Pragma("unroll")                                        \
                for (int j_ = 0; j_ < 2; ++j_)                           \
                    acc[(IOFF) + i_][(JOFF) + j_] =                      \
                        __builtin_amdgcn_mfma_f32_16x16x32_bf16(         \
                            a_f[i_][s_], b_f[(JOFF) + j_][s_],           \
                            acc[(IOFF) + i_][(JOFF) + j_], 0, 0, 0);     \
        __builtin_amdgcn_s_setprio(0);                                   \
    } while (0)

// ---------------------------------------------------------------------------
// bf16 MFMA GEMM, z-batched, 256x256-tile 8-phase schedule (T2+T3+T4+T5).
// BK=64, 512 thr = 8 waves (2M x 4N), per-wave output 128x64.
// LDS 128 KiB: [2 buf][256][64] for A and B, XOR swizzle byte^=(row&7)<<4
// applied as pre-swizzled global source (linear gload_lds dest) + swizzled
// ds_read addr.  Counted vmcnt(6) at phases 4/8 only (never 0 in main loop).
// NTAPS=3 folds K=3 conv taps (zero pad via zero-page redirect).
// EPI: 0 relu; 1 relu+res; 2 relu+res+pe[idxp]+ee[idxe]
// ---------------------------------------------------------------------------
template<int NTAPS, int EPI, int NZ>
__global__ __launch_bounds__(512) void gemm256_kernel(
    GArgs<NZ> ga, const float* __restrict__ res, const float* __restrict__ pe,
    const float* __restrict__ ee, const int* __restrict__ idxp,
    const int* __restrict__ idxe, const ushort* __restrict__ zp)
{
    constexpr int KTOT = NTAPS * 512;
    constexpr int NT   = KTOT / 64;          // K-tiles (8 or 24), even
    const int z = (NZ > 1) ? blockIdx.z : 0;
    const ushort* __restrict__ A    = ga.A[z];
    const ushort* __restrict__ Bt   = ga.W[z];
    const float*  __restrict__ bias = ga.bias[z];
    ushort*       __restrict__ C    = ga.C[z];

    __shared__ ushort As[2][256][64];        // 64 KiB
    __shared__ ushort Bs[2][256][64];        // 64 KiB

    const int tid  = threadIdx.x;
    const int n0   = blockIdx.x * 256;
    const int m0   = blockIdx.y * 256;
    const int lane = tid & 63;
    const int w    = tid >> 6;               // 0..7
    const int wr   = w >> 2;                 // 0..1 -> rows wr*128
    const int wc   = w & 3;                  // 0..3 -> cols wc*64
    const int lr   = lane & 15;
    const int q    = lane >> 4;

    // ---- staging constants (linear LDS dest, pre-swizzled global col) ----
    const int srow = tid >> 3;                        // 0..63 (row within half, r adds 64)
    const int scol = ((tid & 7) ^ (srow & 7)) << 3;   // pre-swizzled col (elements)

    auto stageA = [&](int buf, int h, int kt) {
        const int tap = (NTAPS == 3) ? (kt >> 3) : 0;
        const int kin = (NTAPS == 3) ? ((kt & 7) << 6) : (kt << 6);
        #pragma unroll
        for (int r = 0; r < 2; ++r) {
            const int row = h * 128 + r * 64 + srow;
            const int m   = m0 + row;
            const ushort* src;
            if (NTAPS == 3) {
                const int ls = (m & (Lv - 1)) + tap - 1;
                src = ((unsigned)ls < (unsigned)Lv)
                    ? A + (size_t)(m + tap - 1) * 512 + kin + scol
                    : zp;
            } else {
                src = A + (size_t)m * 512 + kin + scol;
            }
            GLL16(src, ((ushort*)As) + buf * 16384 + h * 8192 + r * 4096 + tid * 8);
        }
    };
    auto stageB = [&](int buf, int h, int kt) {
        #pragma unroll
        for (int r = 0; r < 2; ++r) {
            const int n = n0 + h * 128 + r * 64 + srow;
            const ushort* src = Bt + (size_t)n * KTOT + kt * 64 + scol;
            GLL16(src, ((ushort*)Bs) + buf * 16384 + h * 8192 + r * 4096 + tid * 8);
        }
    };

    // ---- fragment reads (swizzled byte col) ----
    const int ca0 = ((q * 16) ^ ((lr & 7) << 4)) >> 1;        // s=0, elements
    const int ca1 = (((64 + q * 16)) ^ ((lr & 7) << 4)) >> 1; // s=1, elements
    auto readA = [&](int buf, int i8, int s) -> bf16x8 {
        const int rm = wr * 128 + i8 * 16 + lr;
        return *(const bf16x8*)(((const ushort*)As) + buf * 16384 + rm * 64 + (s ? ca1 : ca0));
    };
    auto readB = [&](int buf, int j, int s) -> bf16x8 {
        const int rn = wc * 64 + j * 16 + lr;
        return *(const bf16x8*)(((const ushort*)Bs) + buf * 16384 + rn * 64 + (s ? ca1 : ca0));
    };

    f32x4 acc[8][4];
    #pragma unroll
    for (int i = 0; i < 8; ++i)
        #pragma unroll
        for (int j = 0; j < 4; ++j) {
            f32x4 zz = {0.f, 0.f, 0.f, 0.f};
            acc[i][j] = zz;
        }
    bf16x8 a_f[4][2], b_f[4][2];

    // ---- prologue: t0 fully, t1 minus A-hi (that is iter0-ph1's stage) ----
    stageA(0, 0, 0); stageA(0, 1, 0);
    stageB(0, 0, 0); stageB(0, 1, 0);
    stageA(1, 0, 1);
    stageB(1, 0, 1); stageB(1, 1, 1);
    VMCNT(6);                                 // t0's 8 loads landed
    BAR();

    #pragma unroll 1
    for (int t = 0; t < NT; t += 2) {
        const bool pf = (t + 2 < NT);
        // -------- phase 1: ds A-lo(b0)+B-lo(b0); stage A-hi(t+1)->b1 --------
        #pragma unroll
        for (int i = 0; i < 4; ++i) { a_f[i][0] = readA(0, i, 0); a_f[i][1] = readA(0, i, 1); }
        #pragma unroll
        for (int j = 0; j < 2; ++j) { b_f[j][0] = readB(0, j, 0); b_f[j][1] = readB(0, j, 1); }
        stageA(1, 1, t + 1);
        BAR();
        MFMA_Q(0, 0);
        BAR();
        // -------- phase 2: ds B-hi(b0); stage A-lo(t+2)->b0 --------
        #pragma unroll
        for (int j = 2; j < 4; ++j) { b_f[j][0] = readB(0, j, 0); b_f[j][1] = readB(0, j, 1); }
        if (pf) stageA(0, 0, t + 2);
        BAR();
        MFMA_Q(0, 2);
        BAR();
        // -------- phase 3: ds A-hi(b0); stage B-lo(t+2)->b0 --------
        #pragma unroll
        for (int i = 0; i < 4; ++i) { a_f[i][0] = readA(0, 4 + i, 0); a_f[i][1] = readA(0, 4 + i, 1); }
        if (pf) stageB(0, 0, t + 2);
        BAR();
        MFMA_Q(4, 0);
        BAR();
        // -------- phase 4: stage B-hi(t+2)->b0; counted vmcnt --------
        if (pf) { stageB(0, 1, t + 2); VMCNT(6); }   // waits t+1 fully staged
        else    { VMCNT(0); }                        // final iter: drain A-hi(t+1)
        BAR();
        MFMA_Q(4, 2);
        BAR();
        // -------- phase 5: ds A-lo(b1)+B-lo(b1); stage A-hi(t+2)->b0 --------
        #pragma unroll
        for (int i = 0; i < 4; ++i) { a_f[i][0] = readA(1, i, 0); a_f[i][1] = readA(1, i, 1); }
        #pragma unroll
        for (int j = 0; j < 2; ++j) { b_f[j][0] = readB(1, j, 0); b_f[j][1] = readB(1, j, 1); }
        if (pf) stageA(0, 1, t + 2);
        BAR();
        MFMA_Q(0, 0);
        BAR();
        // -------- phase 6: ds B-hi(b1); stage A-lo(t+3)->b1 --------
        #pragma unroll
        for (int j = 2; j < 4; ++j) { b_f[j][0] = readB(1, j, 0); b_f[j][1] = readB(1, j, 1); }
        if (pf) stageA(1, 0, t + 3);
        BAR();
        MFMA_Q(0, 2);
        BAR();
        // -------- phase 7: ds A-hi(b1); stage B-lo(t+3)->b1 --------
        #pragma unroll
        for (int i = 0; i < 4; ++i) { a_f[i][0] = readA(1, 4 + i, 0); a_f[i][1] = readA(1, 4 + i, 1); }
        if (pf) stageB(1, 0, t + 3);
        BAR();
        MFMA_Q(4, 0);
        BAR();
        // -------- phase 8: stage B-hi(t+3)->b1; counted vmcnt --------
        if (pf) stageB(1, 1, t + 3);
        VMCNT(6);                                    // waits t+2 fully staged
        BAR();
        MFMA_Q(4, 2);
        BAR();
    }

    // epilogue: C/D layout col = lane&15 (n), row = q*4 + reg
    #pragma unroll
    for (int i = 0; i < 8; ++i) {
        #pragma unroll
        for (int r = 0; r < 4; ++r) {
            const int m = m0 + wr * 128 + i * 16 + q * 4 + r;
            const size_t ro = (size_t)m * 512;
            int ip = 0, ie = 0;
            if (EPI == 2) { ip = idxp[m]; ie = idxe[m]; }
            #pragma unroll
            for (int j = 0; j < 4; ++j) {
                const int n = n0 + wc * 64 + j * 16 + lr;
                float v = acc[i][j][r] + bias[n];
                v = fmaxf(v, 0.f);
                if (EPI >= 1) v += res[ro + n];
                if (EPI == 2) v += pe[(size_t)ip * 512 + n] + ee[(size_t)ie * 512 + n];
                C[ro + n] = f2b(v);
            }
        }
    }
}

// ---------------------------------------------------------------------------
// fp32 -> bf16 convert, z-batched over {x, emb}
// ---------------------------------------------------------------------------
__global__ __launch_bounds__(256) void convert_kernel(ConvArgs ca)
{
    const float* __restrict__ X  = ca.src[blockIdx.y];
    ushort*      __restrict__ Xb = ca.dst[blockIdx.y];
    const size_t i = (size_t)blockIdx.x * 256 + threadIdx.x;
    const float4 a = ((const float4*)X)[2 * i];
    const float4 b = ((const float4*)X)[2 * i + 1];
    u16x8 o;
    o[0] = f2b(a.x); o[1] = f2b(a.y); o[2] = f2b(a.z); o[3] = f2b(a.w);
    o[4] = f2b(b.x); o[5] = f2b(b.y); o[6] = f2b(b.z); o[7] = f2b(b.w);
    *(u16x8*)(Xb + i * 8) = o;
}

// ---------------------------------------------------------------------------
// Weight transpose+convert, z-batched: W[kk][n] fp32 -> Wt[n][kk] bf16
// ---------------------------------------------------------------------------
__global__ __launch_bounds__(256) void transpose_kernel(TransArgs ta, int Ktot)
{
    const float* __restrict__ W  = ta.src[blockIdx.z];
    ushort*      __restrict__ Wt = ta.dst[blockIdx.z];
    __shared__ float t[32][33];
    const int k0 = blockIdx.x * 32, n0 = blockIdx.y * 32;
    const int r = threadIdx.x >> 5, c = threadIdx.x & 31;
    #pragma unroll
    for (int rr = 0; rr < 4; ++rr)
        t[r + rr * 8][c] = W[(size_t)(k0 + r + rr * 8) * 512 + n0 + c];
    __syncthreads();
    #pragma unroll
    for (int rr = 0; rr < 4; ++rr)
        Wt[(size_t)(n0 + r + rr * 8) * Ktot + k0 + c] = f2b(t[c][r + rr * 8]);
}

// ---------------------------------------------------------------------------
// RMSNorm, z-batched (grid.y = chain). bf16 in/out, fp32 math.
// ---------------------------------------------------------------------------
__global__ __launch_bounds__(128) void rms_kernel(RmsArgs ra)
{
    const int z = blockIdx.y;
    const int row = blockIdx.x;
    const int tid = threadIdx.x;
    const ushort* __restrict__ h = ra.h[z];
    const ushort4 hv = ((const ushort4*)(h + (size_t)row * 512))[tid];
    const float v0 = b2f(hv.x), v1 = b2f(hv.y), v2 = b2f(hv.z), v3 = b2f(hv.w);
    float ss = v0 * v0 + v1 * v1 + v2 * v2 + v3 * v3;
    #pragma unroll
    for (int off = 32; off; off >>= 1) ss += __shfl_down(ss, off, 64);
    __shared__ float p[2];
    if ((tid & 63) == 0) p[tid >> 6] = ss;
    __syncthreads();
    const float tot = p[0] + p[1];
    const float inv = 1.f / (sqrtf(tot * (1.f / 512.f)) + 1e-8f);
    const float4 gv = ((const float4*)ra.g[z])[tid];
    ushort4 ov;
    ov.x = f2b(gv.x * v0 * inv); ov.y = f2b(gv.y * v1 * inv);
    ov.z = f2b(gv.z * v2 * inv); ov.w = f2b(gv.w * v3 * inv);
    ((ushort4*)(ra.o[z] + (size_t)row * 512))[tid] = ov;
}

// ---------------------------------------------------------------------------
// Fused RMSNorm + linear head, z-batched. pred = mask ? 0 : inv*sum(g*h*wl)+bl
// ---------------------------------------------------------------------------
__global__ __launch_bounds__(256) void rmslin_kernel(
    RlArgs ra, const unsigned char* __restrict__ mask, float* __restrict__ predbase)
{
    const int z = blockIdx.y;
    const int wave = threadIdx.x >> 6, lane = threadIdx.x & 63;
    const int row = blockIdx.x * 4 + wave;
    const ushort* __restrict__ h = ra.h[z];
    const bf16x8 hv = *(const bf16x8*)(h + (size_t)row * 512 + lane * 8);
    const float4 g0 = *(const float4*)(ra.g[z] + lane * 8);
    const float4 g1 = *(const float4*)(ra.g[z] + lane * 8 + 4);
    const float4 w0 = *(const float4*)(ra.wl[z] + lane * 8);
    const float4 w1 = *(const float4*)(ra.wl[z] + lane * 8 + 4);
    float hf[8];
    #pragma unroll
    for (int t = 0; t < 8; ++t) hf[t] = b2f((ushort)hv[t]);
    float ss = 0.f, sgw = 0.f;
    #pragma unroll
    for (int t = 0; t < 8; ++t) ss += hf[t] * hf[t];
    sgw += hf[0]*g0.x*w0.x + hf[1]*g0.y*w0.y + hf[2]*g0.z*w0.z + hf[3]*g0.w*w0.w;
    sgw += hf[4]*g1.x*w1.x + hf[5]*g1.y*w1.y + hf[6]*g1.z*w1.z + hf[7]*g1.w*w1.w;
    #pragma unroll
    for (int off = 32; off; off >>= 1) {
        ss  += __shfl_down(ss,  off, 64);
        sgw += __shfl_down(sgw, off, 64);
    }
    if (lane == 0) {
        const float inv = 1.f / (sqrtf(ss * (1.f / 512.f)) + 1e-8f);
        predbase[(size_t)z * Mv + row] = mask[row] ? 0.f : (sgw * inv + ra.bl[z][0]);
    }
}

// ---------------------------------------------------------------------------
// searchsorted(bins, v, 'left') for pitch & energy targets
// ---------------------------------------------------------------------------
__global__ __launch_bounds__(256) void idx_kernel(
    const float* __restrict__ pt, const float* __restrict__ et,
    const float* __restrict__ pbins, const float* __restrict__ ebins,
    int* __restrict__ idxp, int* __restrict__ idxe)
{
    __shared__ float pb[NBINSv - 1], ebn[NBINSv - 1];
    const int tid = threadIdx.x;
    if (tid < NBINSv - 1) { pb[tid] = pbins[tid]; ebn[tid] = ebins[tid]; }
    __syncthreads();
    const int m = blockIdx.x * 256 + tid;
    const float pv = pt[m], ev = et[m];
    int lo = 0, hi = NBINSv - 1;
    while (lo < hi) { int mid = (lo + hi) >> 1; if (pb[mid] < pv) lo = mid + 1; else hi = mid; }
    idxp[m] = lo;
    lo = 0; hi = NBINSv - 1;
    while (lo < hi) { int mid = (lo + hi) >> 1; if (ebn[mid] < ev) lo = mid + 1; else hi = mid; }
    idxe[m] = lo;
}

// ---------------------------------------------------------------------------
// Per-batch inclusive cumsum of durations, plus mel_len
// ---------------------------------------------------------------------------
__global__ __launch_bounds__(512) void cumsum_kernel(
    const int* __restrict__ dur, int* __restrict__ cum,
    int* __restrict__ melint, float* __restrict__ melout)
{
    __shared__ int s[Lv];
    const int b = blockIdx.x, tid = threadIdx.x;
    s[tid] = dur[b * Lv + tid];
    __syncthreads();
    for (int off = 1; off < Lv; off <<= 1) {
        int t = (tid >= off) ? s[tid - off] : 0;
        __syncthreads();
        s[tid] += t;
        __syncthreads();
    }
    cum[b * Lv + tid] = s[tid];
    if (tid == Lv - 1) { melint[b] = s[tid]; melout[b] = (float)s[tid]; }
}

// ---------------------------------------------------------------------------
// Precompute regulate source map: tmap[b,t] = t < mel_len[b] ? src_row : -1
// ---------------------------------------------------------------------------
__global__ __launch_bounds__(256) void tmap_kernel(
    const int* __restrict__ cum, const int* __restrict__ melint,
    int* __restrict__ tmap)
{
    const int bt = blockIdx.x * 256 + threadIdx.x;
    const int b = bt >> 12;
    const int t = bt & (Tv - 1);
    const int* c = cum + b * Lv;
    int lo = 0, hi = Lv;
    while (lo < hi) { int mid = (lo + hi) >> 1; if (c[mid] <= t) lo = mid + 1; else hi = mid; }
    tmap[bt] = (t < melint[b]) ? (b * Lv + min(lo, Lv - 1)) : -1;
}

// ---------------------------------------------------------------------------
// Length regulate gather: out[bt,:] = tmap[bt] >= 0 ? xo[tmap[bt],:] : 0
// ---------------------------------------------------------------------------
__global__ __launch_bounds__(128) void regulate_kernel(
    const ushort* __restrict__ xo, const int* __restrict__ tmap,
    float* __restrict__ out)
{
    const int bt = blockIdx.x;
    const int src = tmap[bt];
    float4 v = make_float4(0.f, 0.f, 0.f, 0.f);
    if (src >= 0) {
        const ushort4 u = ((const ushort4*)(xo + (size_t)src * 512))[threadIdx.x];
        v.x = b2f(u.x); v.y = b2f(u.y); v.z = b2f(u.z); v.w = b2f(u.w);
    }
    ((float4*)(out + (size_t)bt * 512))[threadIdx.x] = v;
}

// ---------------------------------------------------------------------------
extern "C" void kernel_launch(void* const* d_in, const int* in_sizes, int n_in,
                              void* d_out, int out_size, void* d_ws, size_t ws_size,
                              hipStream_t stream)
{
    const float* x    = (const float*)d_in[0];
    const float* emb  = (const float*)d_in[1];
    const unsigned char* mask = (const unsigned char*)d_in[2];
    const int*   durt = (const int*)d_in[3];
    const float* pt   = (const float*)d_in[4];
    const float* et   = (const float*)d_in[5];
    const float* dw1 = (const float*)d_in[7],  *db1 = (const float*)d_in[8],
               * dg1 = (const float*)d_in[9],  *dw2 = (const float*)d_in[10],
               * db2 = (const float*)d_in[11], *dg2 = (const float*)d_in[12],
               * dwl = (const float*)d_in[13], *dbl = (const float*)d_in[14];
    const float* pw1 = (const float*)d_in[15], *pb1 = (const float*)d_in[16],
               * pg1 = (const float*)d_in[17], *pw2 = (const float*)d_in[18],
               * pb2 = (const float*)d_in[19], *pg2 = (const float*)d_in[20],
               * pwl = (const float*)d_in[21], *pbl = (const float*)d_in[22];
    const float* ew1 = (const float*)d_in[23], *eb1 = (const float*)d_in[24],
               * eg1 = (const float*)d_in[25], *ew2 = (const float*)d_in[26],
               * eb2 = (const float*)d_in[27], *eg2 = (const float*)d_in[28],
               * ewl = (const float*)d_in[29], *ebl = (const float*)d_in[30];
    const float* ppw1 = (const float*)d_in[31], *ppb1 = (const float*)d_in[32],
               * ppw2 = (const float*)d_in[33], *ppb2 = (const float*)d_in[34];
    const float* epw1 = (const float*)d_in[35], *epb1 = (const float*)d_in[36],
               * epw2 = (const float*)d_in[37], *epb2 = (const float*)d_in[38];
    const float* spw1 = (const float*)d_in[39], *spb1 = (const float*)d_in[40],
               * spw2 = (const float*)d_in[41], *spb2 = (const float*)d_in[42];
    const float* pbins = (const float*)d_in[43];
    const float* ebins = (const float*)d_in[44];
    const float* pemb  = (const float*)d_in[45];
    const float* eemb  = (const float*)d_in[46];

    float* outf = (float*)d_out;

    // ---- ws scratch (int offsets) ----
    int*    cum    = (int*)d_ws;                    // 16384
    int*    melint = cum + 16384;                   // 64
    int*    idxp   = melint + 64;                   // 16384
    int*    idxe   = idxp + 16384;                  // 16384
    ushort* zp     = (ushort*)(idxe + 16384);       // 32 ushorts (16B-aligned)
    int*    tmap   = idxe + 16448;                  // 131072
    ushort* xob    = (ushort*)((float*)d_ws + 262144);  // Mv*512 bf16, 1MB offset

    // ---- d_out front scratch (float offsets; regulate overwrites all) ----
    #define OBUF(i) ((ushort*)(outf + (size_t)(i) * 4194304))
    ushort* xb  = OBUF(0);   ushort* eb  = OBUF(1);
    ushort* pA0 = OBUF(2);   ushort* pA1 = OBUF(3);  ushort* pA2 = OBUF(4);
    ushort* xp  = OBUF(5);   ushort* xe  = OBUF(6);
    ushort* c0  = OBUF(7);   ushort* c1  = OBUF(8);  ushort* c2  = OBUF(9);
    ushort* r0  = OBUF(10);  ushort* r1  = OBUF(11); ushort* r2  = OBUF(12);
    ushort* wt[12];
    {
        size_t off = 13ull * 4194304;
        for (int i = 0; i < 6; ++i)  { wt[i] = (ushort*)(outf + off); off += 393216; }  // conv 1536x512
        for (int i = 6; i < 12; ++i) { wt[i] = (ushort*)(outf + off); off += 131072; }  // proj 512x512
    }

    hipMemsetAsync(zp, 0, 64, stream);

    // converts + transposes (batched)
    { ConvArgs ca = {{x, emb}, {xb, eb}};
      convert_kernel<<<dim3(4096, 2), 256, 0, stream>>>(ca); }
    { TransArgs ta = {{dw1, dw2, pw1, pw2, ew1, ew2}, {wt[0], wt[1], wt[2], wt[3], wt[4], wt[5]}};
      transpose_kernel<<<dim3(48, 16, 6), 256, 0, stream>>>(ta, 1536); }
    { TransArgs ta = {{ppw1, ppw2, epw1, epw2, spw1, spw2},
                      {wt[6], wt[7], wt[8], wt[9], wt[10], wt[11]}};
      transpose_kernel<<<dim3(16, 16, 6), 256, 0, stream>>>(ta, 512); }

    idx_kernel<<<Mv / 256, 256, 0, stream>>>(pt, et, pbins, ebins, idxp, idxe);
    cumsum_kernel<<<Bv, Lv, 0, stream>>>(durt, cum, melint, outf + MEL_OFF);
    tmap_kernel<<<Bv * Tv / 256, 256, 0, stream>>>(cum, melint, tmap);

    const dim3 g3(Fv / 256, Mv / 256, 3);   // (2, 64, 3)
    const dim3 g2(Fv / 256, Mv / 256, 2);
    const dim3 g1(Fv / 256, Mv / 256, 1);

    // proj1: h = relu(emb @ w1 + b1) for pp/ep/sp
    { GArgs<3> a = {{eb, eb, eb}, {wt[6], wt[8], wt[10]}, {ppb1, epb1, spb1}, {pA0, pA1, pA2}};
      gemm256_kernel<1, 0, 3><<<g3, 512, 0, stream>>>(a, nullptr, nullptr, nullptr,
                                                      nullptr, nullptr, zp); }
    // proj2 pp/ep: xin = x + relu(h @ w2 + b2)
    { GArgs<2> a = {{pA0, pA1}, {wt[7], wt[9]}, {ppb2, epb2}, {xp, xe}};
      gemm256_kernel<1, 1, 2><<<g2, 512, 0, stream>>>(a, x, nullptr, nullptr,
                                                      nullptr, nullptr, zp); }
    // proj2 sp: xo = x + pe + ee + relu(h @ w2 + b2)
    { GArgs<1> a = {{pA2}, {wt[11]}, {spb2}, {xob}};
      gemm256_kernel<1, 2, 1><<<g1, 512, 0, stream>>>(a, x, pemb, eemb, idxp, idxe, zp); }

    // conv1 for {pit, eng, dur}
    { GArgs<3> a = {{xp, xe, xb}, {wt[2], wt[4], wt[0]}, {pb1, eb1, db1}, {c0, c1, c2}};
      gemm256_kernel<3, 0, 3><<<g3, 512, 0, stream>>>(a, nullptr, nullptr, nullptr,
                                                      nullptr, nullptr, zp); }
    { RmsArgs ra = {{c0, c1, c2}, {pg1, eg1, dg1}, {r0, r1, r2}};
      rms_kernel<<<dim3(Mv, 3), 128, 0, stream>>>(ra); }
    // conv2
    { GArgs<3> a = {{r0, r1, r2}, {wt[3], wt[5], wt[1]}, {pb2, eb2, db2}, {c0, c1, c2}};
      gemm256_kernel<3, 0, 3><<<g3, 512, 0, stream>>>(a, nullptr, nullptr, nullptr,
                                                      nullptr, nullptr, zp); }
    // fused rms2 + linear head -> preds at PIT|ENG|DUR (contiguous, z-ordered)
    { RlArgs ra = {{c0, c1, c2}, {pg2, eg2, dg2}, {pwl, ewl, dwl}, {pbl, ebl, dbl}};
      rmslin_kernel<<<dim3(Mv / 4, 3), 256, 0, stream>>>(ra, mask, outf + PIT_OFF); }

    // length regulate gather -> out (overwrites all d_out-front scratch)
    regulate_kernel<<<Bv * Tv, 128, 0, stream>>>(xob, tmap, outf + OUT_OFF);
}